// Round 14
// baseline (38.913 us; speedup 1.0000x reference)
//
#include <hip/hip_runtime.h>

// CrossConvV2 — R13: DIAGNOSTIC round. R12 kernel exactly, REPLICATE=2 so
// our kernel (~47us) outranks the 39us harness poison-fills in rocprof
// top-5 and we get VALUBusy/Occupancy/VGPR for the CURRENT inner loop.
// 6 rounds flat at ~23.7us with no counters = flying blind; buying data.

#define NPTS      1024
#define COEFF     10.0f
#define NEG       0.3f
#define REPLICATE 2

typedef float  v2f __attribute__((ext_vector_type(2)));
typedef __fp16 h2  __attribute__((ext_vector_type(2)));

#define CA 4.24264068f   // 2*2.12132034
#define CY 3.91968890f   // 2*1.95984445
#define CZ 1.62358830f   // 2*0.81179415

// slot -> probe index (R9-validated mapping)
constexpr int M0[14] = {0,5, 1,4, 2,3, 7,6, 8,12, 10,14, 24,25};
constexpr int M1[12] = {16,19, 17,18, 20,23, 21,22, 9,13, 11,15};

__device__ __forceinline__ v2f vfma(float c, v2f a, v2f b) {
#if __has_builtin(__builtin_elementwise_fma)
  return __builtin_elementwise_fma(v2f{c, c}, a, b);
#else
  return v2f{fmaf(c, a.x, b.x), fmaf(c, a.y, b.y)};
#endif
}

// wave64 sum-reduce via DPP (result valid in lane 63). rocPRIM pattern.
#define DPP_STEP(x, ctrl, rm, bm, bc)                                        \
  x += __int_as_float(__builtin_amdgcn_update_dpp(                           \
      0, __float_as_int(x), ctrl, rm, bm, bc))

__device__ __forceinline__ float wave_sum_to_lane63(float x) {
  DPP_STEP(x, 0x111, 0xf, 0xf, true);   // row_shr:1
  DPP_STEP(x, 0x112, 0xf, 0xf, true);   // row_shr:2
  DPP_STEP(x, 0x114, 0xf, 0xe, false);  // row_shr:4
  DPP_STEP(x, 0x118, 0xf, 0xc, false);  // row_shr:8
  DPP_STEP(x, 0x142, 0xa, 0xf, false);  // row_bcast:15 -> rows 1,3
  DPP_STEP(x, 0x143, 0xc, 0xf, false);  // row_bcast:31 -> rows 2,3
  return x;                              // lane 63 = full sum
}

// t-slot generation, v2f over the neighbor pair. R9's CSE structure.
template <int HALF>
__device__ __forceinline__ void tgen(v2f dx, v2f dy, v2f dz, v2f base, v2f* t) {
  if constexpr (HALF == 0) {
    const v2f rx = vfma( CA, dx, base);   // ring x=-2.1213
    const v2f sA = vfma( CZ, dz, rx);
    const v2f sB = vfma(-CZ, dz, rx);
    const v2f sC = vfma(-CY, dz, rx);
    const v2f sD = vfma( CY, dz, rx);
    t[0]  = vfma(-CY, dy, sA);   t[1]  = vfma( CY, dy, sA);   // p0,p5
    t[2]  = vfma(-CY, dy, sB);   t[3]  = vfma( CY, dy, sB);   // p1,p4
    t[4]  = vfma(-CZ, dy, sC);   t[5]  = vfma( CZ, dy, sC);   // p2,p3
    t[6]  = vfma(-CZ, dy, sD);   t[7]  = vfma( CZ, dy, sD);   // p7,p6
    t[8]  = vfma(-6.f, dy, base); t[9]  = vfma( 6.f, dy, base); // p8,p12
    t[10] = vfma(-6.f, dz, base); t[11] = vfma( 6.f, dz, base); // p10,p14
    t[12] = vfma( 6.f, dx, base); t[13] = vfma(-6.f, dx, base); // p24,p25
  } else {
    const v2f rx = vfma(-CA, dx, base);   // ring x=+2.1213
    const v2f sA = vfma(-CZ, dz, rx);
    const v2f sB = vfma(-CY, dz, rx);
    const v2f sC = vfma( CZ, dz, rx);
    const v2f sD = vfma( CY, dz, rx);
    const v2f u = dy + dz, v = dy - dz;
    t[0]  = vfma(-CY, dy, sA);   t[1]  = vfma( CY, dy, sA);   // p16,p19
    t[2]  = vfma(-CZ, dy, sB);   t[3]  = vfma( CZ, dy, sB);   // p17,p18
    t[4]  = vfma( CY, dy, sC);   t[5]  = vfma(-CY, dy, sC);   // p20,p23
    t[6]  = vfma( CZ, dy, sD);   t[7]  = vfma(-CZ, dy, sD);   // p21,p22
    t[8]  = vfma(-CA, u, base);  t[9]  = vfma( CA, u, base);  // p9,p13
    t[10] = vfma( CA, v, base);  t[11] = vfma(-CA, v, base);  // p11,p15
  }
}

template <int HALF>
__device__ void run_main(const float* __restrict__ batch, int lane,
                         float cx, float cy, float cz, float* acc) {
  constexpr int NP = HALF ? 12 : 14;
  for (int it = 0; it < NPTS / 128; ++it) {    // neighbors A,B per step
    const float* prowA = batch + (it * 128 + lane) * 6;
    const float* prowB = prowA + 64 * 6;
    const float2 a0 = *reinterpret_cast<const float2*>(prowA);
    const float2 a1 = *reinterpret_cast<const float2*>(prowA + 2);
    const float2 a2 = *reinterpret_cast<const float2*>(prowA + 4);
    const float2 b0 = *reinterpret_cast<const float2*>(prowB);
    const float2 b1 = *reinterpret_cast<const float2*>(prowB + 2);
    const float2 b2 = *reinterpret_cast<const float2*>(prowB + 4);

    const v2f dx = v2f{a0.x, b0.x} - cx;
    const v2f dy = v2f{a0.y, b0.y} - cy;
    const v2f dz = v2f{a1.x, b1.x} - cz;
    v2f base = vfma(1.f, dz * dz, v2f{19.f, 19.f});
    base = __builtin_elementwise_fma(dy, dy, base);
    base = __builtin_elementwise_fma(dx, dx, base);

    v2f t[NP];
    tgen<HALF>(dx, dy, dz, base, t);

    // f16-packed features across the pair
    const h2 f0p = __builtin_amdgcn_cvt_pkrtz(a1.y, b1.y);
    const h2 f1p = __builtin_amdgcn_cvt_pkrtz(a2.x, b2.x);
    const h2 f2p = __builtin_amdgcn_cvt_pkrtz(a2.y, b2.y);

    #pragma unroll
    for (int j = 0; j < NP; ++j) {
      // rcp2 across the neighbor pair: w = {1/tA, 1/tB}
      const float r  = __builtin_amdgcn_rcpf(t[j].x * t[j].y);
      const h2 wp = __builtin_amdgcn_cvt_pkrtz(t[j].y * r, t[j].x * r);
      acc[j * 3 + 0] = __builtin_amdgcn_fdot2(wp, f0p, acc[j * 3 + 0], false);
      acc[j * 3 + 1] = __builtin_amdgcn_fdot2(wp, f1p, acc[j * 3 + 1], false);
      acc[j * 3 + 2] = __builtin_amdgcn_fdot2(wp, f2p, acc[j * 3 + 2], false);
    }
  }
}

template <int HALF>
__device__ __forceinline__ void reduce_store(float* acc, int lane, float* sx) {
  constexpr int NP = HALF ? 12 : 14;
  #pragma unroll
  for (int j = 0; j < NP * 3; ++j)
    acc[j] = wave_sum_to_lane63(acc[j]);
  if (lane == 63) {
    #pragma unroll
    for (int j = 0; j < NP; ++j) {
      const int m = HALF ? M1[j] : M0[j];
      sx[m * 3 + 0] = acc[j * 3 + 0];
      sx[m * 3 + 1] = acc[j * 3 + 1];
      sx[m * 3 + 2] = acc[j * 3 + 2];
    }
  }
}

__global__ __launch_bounds__(256, 4) void crossconv_kernel(
    const float* __restrict__ points,  // (2,1024,6)
    const float* __restrict__ W,       // (5,78,6)
    const float* __restrict__ bias,    // (5,6) flat 30
    float* __restrict__ out)           // (2,1024,33)
{
    __shared__ __align__(16) float sx[2][80];

    const int tid    = threadIdx.x;
    const int lane   = tid & 63;
    const int w      = tid >> 6;          // wave in block: 0..3
    const int cLocal = w >> 1;            // center within block: 0,1
    const int half   = w & 1;             // probe half: 0,1
    const int bid    = blockIdx.x & 1023; // REPLICATE copies, same output
    const int G      = bid * 2 + cLocal;  // global center 0..2047

    const float* batch = points + (G >> 10) * (NPTS * 6);
    const float* crow  = points + G * 6;
    const float  cx = crow[0], cy = crow[1], cz = crow[2];

    float acc[42];
    #pragma unroll
    for (int j = 0; j < 42; ++j) acc[j] = 0.f;

    if (half == 0) run_main<0>(batch, lane, cx, cy, cz, acc);
    else           run_main<1>(batch, lane, cx, cy, cz, acc);

    if (half == 0) reduce_store<0>(acc, lane, sx[cLocal]);
    else           reduce_store<1>(acc, lane, sx[cLocal]);
    __syncthreads();

    // tail: waves with half==0 do the 78->30 matmul + coords for their center
    if (half == 0) {
      const float scale = COEFF / (float)NPTS;   // folded here
      float* orow = out + G * 33;
      if (lane < 30) {
        const int k = lane / 6, o = lane % 6;
        const float* Wk = W + k * (78 * 6) + o;  // W[k, t, o], stride 6 over t
        float h0 = 0.f, h1 = 0.f, h2_ = 0.f, h3 = 0.f;
        const float4* sxv = reinterpret_cast<const float4*>(sx[cLocal]);
        #pragma unroll
        for (int t4 = 0; t4 < 19; ++t4) {
          const float4 v = sxv[t4];
          h0  = fmaf(v.x, Wk[(t4 * 4 + 0) * 6], h0);
          h1  = fmaf(v.y, Wk[(t4 * 4 + 1) * 6], h1);
          h2_ = fmaf(v.z, Wk[(t4 * 4 + 2) * 6], h2_);
          h3  = fmaf(v.w, Wk[(t4 * 4 + 3) * 6], h3);
        }
        const float2 vt = *reinterpret_cast<const float2*>(&sx[cLocal][76]);
        h0 = fmaf(vt.x, Wk[76 * 6], h0);
        h1 = fmaf(vt.y, Wk[77 * 6], h1);
        const float dot = (h0 + h2_) + (h1 + h3);
        float h = fmaf(dot, scale, bias[lane]);
        h = (h > 0.f) ? h : NEG * h;
        orow[3 + lane] = h;
      } else if (lane < 33) {
        orow[lane - 30] = (lane == 30) ? cx : ((lane == 31) ? cy : cz);
      }
    }
}

extern "C" void kernel_launch(void* const* d_in, const int* in_sizes, int n_in,
                              void* d_out, int out_size, void* d_ws, size_t ws_size,
                              hipStream_t stream) {
    const float* points = (const float*)d_in[0];  // 2*1024*6
    const float* W      = (const float*)d_in[1];  // 5*78*6
    const float* bias   = (const float*)d_in[2];  // 30
    float* out          = (float*)d_out;          // 2*1024*33
    // 1024 logical blocks x REPLICATE (identical outputs) — diagnostic:
    // pushes our kernel above the 39us harness fills into rocprof top-5
    crossconv_kernel<<<1024 * REPLICATE, 256, 0, stream>>>(points, W, bias, out);
}

// Round 15
// 23.818 us; speedup vs baseline: 1.6337x; 1.6337x over previous
//
#include <hip/hip_runtime.h>

// CrossConvV2 — R14. R13 counters: VALUBusy 60%, fixed ~8.6us + marginal
// ~15.1us; rcp path = 50% of per-wave issue, reduce = 19%. Changes:
//  1) real v_pk_fma_f32/v_pk_add_f32 via asm — ALL operands v2f pairs
//     (R11 lesson), signs via neg_lo/neg_hi, splat consts hoisted.
//  2) rcp8 batching: 1 rcp per 8 values (21 mul + 1 rcp + 4 cvt / 8 vals).
//  3) f16x2-packed DPP reduce (v_pk_add_f16): 2 values per step.

#define NPTS   1024
#define COEFF  10.0f
#define NEG    0.3f

typedef float  v2f __attribute__((ext_vector_type(2)));
typedef __fp16 h2  __attribute__((ext_vector_type(2)));

#define CA 4.24264068f   // 2*2.12132034
#define CY 3.91968890f   // 2*1.95984445
#define CZ 1.62358830f   // 2*0.81179415

// slot -> probe index (R9/R12-validated mapping)
constexpr int M0[14] = {0,5, 1,4, 2,3, 7,6, 8,12, 10,14, 24,25};
constexpr int M1[12] = {16,19, 17,18, 20,23, 21,22, 9,13, 11,15};

// ---- VOP3P packed f32 (all operands are VGPR pairs -> legal encoding) ----
__device__ __forceinline__ v2f pk_fma(v2f a, v2f b, v2f c) {   // a*b+c
  v2f d;
  asm("v_pk_fma_f32 %0, %1, %2, %3" : "=v"(d) : "v"(a), "v"(b), "v"(c));
  return d;
}
__device__ __forceinline__ v2f pk_fma_n(v2f a, v2f b, v2f c) { // -a*b+c
  v2f d;
  asm("v_pk_fma_f32 %0, %1, %2, %3 neg_lo:[1,0,0] neg_hi:[1,0,0]"
      : "=v"(d) : "v"(a), "v"(b), "v"(c));
  return d;
}
__device__ __forceinline__ v2f pk_add(v2f a, v2f b) {          // a+b
  v2f d;
  asm("v_pk_add_f32 %0, %1, %2" : "=v"(d) : "v"(a), "v"(b));
  return d;
}
__device__ __forceinline__ v2f pk_sub(v2f a, v2f b) {          // a-b
  v2f d;
  asm("v_pk_add_f32 %0, %1, %2 neg_lo:[0,1] neg_hi:[0,1]"
      : "=v"(d) : "v"(a), "v"(b));
  return d;
}

// ---- wave64 f32 DPP reduce (valid in lane 63) ----
#define DPP_F32(x, ctrl, rm, bm, bc)                                         \
  x += __int_as_float(__builtin_amdgcn_update_dpp(                           \
      0, __float_as_int(x), ctrl, rm, bm, bc))

// ---- wave64 f16x2 DPP reduce: 2 values per op chain ----
#define DPP_H2(x, ctrl, rm, bm, bc)                                          \
  x = x + __builtin_bit_cast(h2, __builtin_amdgcn_update_dpp(                \
      0, __builtin_bit_cast(int, x), ctrl, rm, bm, bc))

__device__ __forceinline__ h2 h2_wave_sum_to_lane63(h2 x) {
  DPP_H2(x, 0x111, 0xf, 0xf, true);   // row_shr:1
  DPP_H2(x, 0x112, 0xf, 0xf, true);   // row_shr:2
  DPP_H2(x, 0x114, 0xf, 0xe, false);  // row_shr:4
  DPP_H2(x, 0x118, 0xf, 0xc, false);  // row_shr:8
  DPP_H2(x, 0x142, 0xa, 0xf, false);  // row_bcast:15
  DPP_H2(x, 0x143, 0xc, 0xf, false);  // row_bcast:31
  return x;                            // lane 63 = full sum (x2)
}

// ---- rcp8: one v_rcp for 4 t-pairs (8 values); emits packed-f16 w ----
__device__ __forceinline__ void rcp8_cvt(const v2f* t, h2* wp) {
  const float p0 = t[0].x * t[0].y, p1 = t[1].x * t[1].y;
  const float p2 = t[2].x * t[2].y, p3 = t[3].x * t[3].y;
  const float q01 = p0 * p1, q23 = p2 * p3;
  const float r   = __builtin_amdgcn_rcpf(q01 * q23);
  const float r01 = q23 * r, r23 = q01 * r;
  const float i0 = p1 * r01, i1 = p0 * r01;
  const float i2 = p3 * r23, i3 = p2 * r23;
  wp[0] = __builtin_amdgcn_cvt_pkrtz(t[0].y * i0, t[0].x * i0);
  wp[1] = __builtin_amdgcn_cvt_pkrtz(t[1].y * i1, t[1].x * i1);
  wp[2] = __builtin_amdgcn_cvt_pkrtz(t[2].y * i2, t[2].x * i2);
  wp[3] = __builtin_amdgcn_cvt_pkrtz(t[3].y * i3, t[3].x * i3);
}
__device__ __forceinline__ void rcp4_cvt(const v2f* t, h2* wp) {
  const float p0 = t[0].x * t[0].y, p1 = t[1].x * t[1].y;
  const float r  = __builtin_amdgcn_rcpf(p0 * p1);
  const float i0 = p1 * r, i1 = p0 * r;
  wp[0] = __builtin_amdgcn_cvt_pkrtz(t[0].y * i0, t[0].x * i0);
  wp[1] = __builtin_amdgcn_cvt_pkrtz(t[1].y * i1, t[1].x * i1);
}

template <int HALF>
__device__ void run_main(const float* __restrict__ batch, int lane,
                         v2f cxp, v2f cyp, v2f czp, float* acc) {
  constexpr int NP = HALF ? 12 : 14;
  const v2f kCA = {CA, CA}, kCY = {CY, CY}, kCZ = {CZ, CZ};
  const v2f k6 = {6.f, 6.f}, k19 = {19.f, 19.f};

  for (int it = 0; it < NPTS / 128; ++it) {    // neighbors A,B per step
    const float* prowA = batch + (it * 128 + lane) * 6;
    const float* prowB = prowA + 64 * 6;
    const float2 a0 = *reinterpret_cast<const float2*>(prowA);
    const float2 a1 = *reinterpret_cast<const float2*>(prowA + 2);
    const float2 a2 = *reinterpret_cast<const float2*>(prowA + 4);
    const float2 b0 = *reinterpret_cast<const float2*>(prowB);
    const float2 b1 = *reinterpret_cast<const float2*>(prowB + 2);
    const float2 b2 = *reinterpret_cast<const float2*>(prowB + 4);

    const v2f dx = pk_sub(v2f{a0.x, b0.x}, cxp);
    const v2f dy = pk_sub(v2f{a0.y, b0.y}, cyp);
    const v2f dz = pk_sub(v2f{a1.x, b1.x}, czp);
    v2f base = pk_fma(dz, dz, k19);
    base = pk_fma(dy, dy, base);
    base = pk_fma(dx, dx, base);

    v2f t[NP];
    if constexpr (HALF == 0) {
      const v2f rx = pk_fma(kCA, dx, base);     // ring x=-2.1213
      const v2f sA = pk_fma  (kCZ, dz, rx);
      const v2f sB = pk_fma_n(kCZ, dz, rx);
      const v2f sC = pk_fma_n(kCY, dz, rx);
      const v2f sD = pk_fma  (kCY, dz, rx);
      t[0]  = pk_fma_n(kCY, dy, sA);  t[1]  = pk_fma(kCY, dy, sA);  // p0,p5
      t[2]  = pk_fma_n(kCY, dy, sB);  t[3]  = pk_fma(kCY, dy, sB);  // p1,p4
      t[4]  = pk_fma_n(kCZ, dy, sC);  t[5]  = pk_fma(kCZ, dy, sC);  // p2,p3
      t[6]  = pk_fma_n(kCZ, dy, sD);  t[7]  = pk_fma(kCZ, dy, sD);  // p7,p6
      t[8]  = pk_fma_n(k6, dy, base); t[9]  = pk_fma(k6, dy, base); // p8,p12
      t[10] = pk_fma_n(k6, dz, base); t[11] = pk_fma(k6, dz, base); // p10,p14
      t[12] = pk_fma  (k6, dx, base); t[13] = pk_fma_n(k6, dx, base);// p24,p25
    } else {
      const v2f rx = pk_fma_n(kCA, dx, base);   // ring x=+2.1213
      const v2f sA = pk_fma_n(kCZ, dz, rx);
      const v2f sB = pk_fma_n(kCY, dz, rx);
      const v2f sC = pk_fma  (kCZ, dz, rx);
      const v2f sD = pk_fma  (kCY, dz, rx);
      const v2f u = pk_add(dy, dz), v = pk_sub(dy, dz);
      t[0]  = pk_fma_n(kCY, dy, sA);  t[1]  = pk_fma(kCY, dy, sA);  // p16,p19
      t[2]  = pk_fma_n(kCZ, dy, sB);  t[3]  = pk_fma(kCZ, dy, sB);  // p17,p18
      t[4]  = pk_fma  (kCY, dy, sC);  t[5]  = pk_fma_n(kCY, dy, sC);// p20,p23
      t[6]  = pk_fma  (kCZ, dy, sD);  t[7]  = pk_fma_n(kCZ, dy, sD);// p21,p22
      t[8]  = pk_fma_n(kCA, u, base); t[9]  = pk_fma(kCA, u, base); // p9,p13
      t[10] = pk_fma  (kCA, v, base); t[11] = pk_fma_n(kCA, v, base);// p11,p15
    }

    h2 wp[NP];
    rcp8_cvt(t + 0, wp + 0);
    rcp8_cvt(t + 4, wp + 4);
    rcp8_cvt(t + 8, wp + 8);
    if constexpr (NP == 14) rcp4_cvt(t + 12, wp + 12);

    const h2 f0p = __builtin_amdgcn_cvt_pkrtz(a1.y, b1.y);
    const h2 f1p = __builtin_amdgcn_cvt_pkrtz(a2.x, b2.x);
    const h2 f2p = __builtin_amdgcn_cvt_pkrtz(a2.y, b2.y);

    #pragma unroll
    for (int j = 0; j < NP; ++j) {
      acc[j * 3 + 0] = __builtin_amdgcn_fdot2(wp[j], f0p, acc[j * 3 + 0], false);
      acc[j * 3 + 1] = __builtin_amdgcn_fdot2(wp[j], f1p, acc[j * 3 + 1], false);
      acc[j * 3 + 2] = __builtin_amdgcn_fdot2(wp[j], f2p, acc[j * 3 + 2], false);
    }
  }
}

// packed f16x2 reduce of NP*3 accs; lane 63 unpacks into f32 sx
template <int HALF>
__device__ __forceinline__ void reduce_store(float* acc, int lane, float* sx) {
  constexpr int NP = HALF ? 12 : 14;
  constexpr int NH = NP * 3 / 2;            // 21 or 18 h2 regs
  h2 red[NH];
  #pragma unroll
  for (int p = 0; p < NH; ++p)
    red[p] = __builtin_amdgcn_cvt_pkrtz(acc[2 * p], acc[2 * p + 1]);
  #pragma unroll
  for (int p = 0; p < NH; ++p)
    red[p] = h2_wave_sum_to_lane63(red[p]);
  if (lane == 63) {
    #pragma unroll
    for (int p = 0; p < NH; ++p) {
      const int a0 = 2 * p, a1 = 2 * p + 1;
      const int m0 = (HALF ? M1[a0 / 3] : M0[a0 / 3]);
      const int m1 = (HALF ? M1[a1 / 3] : M0[a1 / 3]);
      sx[m0 * 3 + a0 % 3] = (float)red[p].x;
      sx[m1 * 3 + a1 % 3] = (float)red[p].y;
    }
  }
}

__global__ __launch_bounds__(256, 4) void crossconv_kernel(
    const float* __restrict__ points,  // (2,1024,6)
    const float* __restrict__ W,       // (5,78,6)
    const float* __restrict__ bias,    // (5,6) flat 30
    float* __restrict__ out)           // (2,1024,33)
{
    __shared__ __align__(16) float sx[2][80];

    const int tid    = threadIdx.x;
    const int lane   = tid & 63;
    const int w      = tid >> 6;          // wave in block: 0..3
    const int cLocal = w >> 1;            // center within block: 0,1
    const int half   = w & 1;             // probe half: 0,1
    const int G      = blockIdx.x * 2 + cLocal;   // global center 0..2047

    const float* batch = points + (G >> 10) * (NPTS * 6);
    const float* crow  = points + G * 6;
    const float  cx = crow[0], cy = crow[1], cz = crow[2];
    const v2f cxp = {cx, cx}, cyp = {cy, cy}, czp = {cz, cz};

    float acc[42];
    #pragma unroll
    for (int j = 0; j < 42; ++j) acc[j] = 0.f;

    if (half == 0) run_main<0>(batch, lane, cxp, cyp, czp, acc);
    else           run_main<1>(batch, lane, cxp, cyp, czp, acc);

    if (half == 0) reduce_store<0>(acc, lane, sx[cLocal]);
    else           reduce_store<1>(acc, lane, sx[cLocal]);
    __syncthreads();

    // tail: waves with half==0 do the 78->30 matmul + coords for their center
    if (half == 0) {
      const float scale = COEFF / (float)NPTS;
      float* orow = out + G * 33;
      if (lane < 30) {
        const int k = lane / 6, o = lane % 6;
        const float* Wk = W + k * (78 * 6) + o;  // W[k, t, o], stride 6 over t
        float h0 = 0.f, h1 = 0.f, h2_ = 0.f, h3 = 0.f;
        const float4* sxv = reinterpret_cast<const float4*>(sx[cLocal]);
        #pragma unroll
        for (int t4 = 0; t4 < 19; ++t4) {
          const float4 v = sxv[t4];
          h0  = fmaf(v.x, Wk[(t4 * 4 + 0) * 6], h0);
          h1  = fmaf(v.y, Wk[(t4 * 4 + 1) * 6], h1);
          h2_ = fmaf(v.z, Wk[(t4 * 4 + 2) * 6], h2_);
          h3  = fmaf(v.w, Wk[(t4 * 4 + 3) * 6], h3);
        }
        const float2 vt = *reinterpret_cast<const float2*>(&sx[cLocal][76]);
        h0 = fmaf(vt.x, Wk[76 * 6], h0);
        h1 = fmaf(vt.y, Wk[77 * 6], h1);
        const float dot = (h0 + h2_) + (h1 + h3);
        float h = fmaf(dot, scale, bias[lane]);
        h = (h > 0.f) ? h : NEG * h;
        orow[3 + lane] = h;
      } else if (lane < 33) {
        orow[lane - 30] = (lane == 30) ? cx : ((lane == 31) ? cy : cz);
      }
    }
}

extern "C" void kernel_launch(void* const* d_in, const int* in_sizes, int n_in,
                              void* d_out, int out_size, void* d_ws, size_t ws_size,
                              hipStream_t stream) {
    const float* points = (const float*)d_in[0];  // 2*1024*6
    const float* W      = (const float*)d_in[1];  // 5*78*6
    const float* bias   = (const float*)d_in[2];  // 30
    float* out          = (float*)d_out;          // 2*1024*33
    // 1024 blocks x 4 waves = 2048 centers x 2 probe-halves
    crossconv_kernel<<<1024, 256, 0, stream>>>(points, W, bias, out);
}